// Round 1
// baseline (134.405 us; speedup 1.0000x reference)
//
#include <hip/hip_runtime.h>
#include <cmath>

// DotMaskLayer: B=16384, D=256, H=64, M=128.
// keep(j) = (j < K) | (128 <= j < 128+K)  [j=256 bias only if K>128]
// out[b,h] = tanh( sum_j keep(j)*Y[b,j]*W[b,j,h] ),  W = AUX.reshape(B,257,64)

#define D_DIM 256
#define H_DIM 64
#define ROWS 257
#define ROWSTRIDE (ROWS * H_DIM)   // 16448 floats per batch row of AUX

__global__ void dotmask_kernel(const float* __restrict__ X,
                               const float* __restrict__ AUX,
                               const int* __restrict__ K,
                               float* __restrict__ out,
                               int B)
{
    const int lane = threadIdx.x & 63;
    const int wid  = threadIdx.x >> 6;          // wave within block (0..3)
    const int b    = blockIdx.x * 4 + wid;      // one wave per batch row
    if (b >= B) return;

    const int k = K[b];
    const float* __restrict__ Wb = AUX + (size_t)b * ROWSTRIDE;
    const float* __restrict__ Xb = X   + (size_t)b * D_DIM;

    const int jo = lane >> 4;          // row offset within 4-row group (0..3)
    const int h4 = (lane & 15) * 4;    // this lane's 4 consecutive h's

    float ax = 0.f, ay = 0.f, az = 0.f, aw = 0.f;

    // ---- block 1: j in [0, k) ----
    for (int j0 = 0; j0 < k; j0 += 4) {
        const int j = j0 + jo;
        const float xj = (j < k) ? Xb[j] : 0.f;
        const float4 w = *reinterpret_cast<const float4*>(Wb + (size_t)j * H_DIM + h4);
        ax += xj * w.x; ay += xj * w.y; az += xj * w.z; aw += xj * w.w;
    }

    // ---- block 2: j in [128, 128+k) ----
    const int jend = 128 + k;
    for (int j0 = 128; j0 < jend; j0 += 4) {
        const int j = j0 + jo;
        const float xj = (j < jend) ? Xb[j] : 0.f;
        const float4 w = *reinterpret_cast<const float4*>(Wb + (size_t)j * H_DIM + h4);
        ax += xj * w.x; ay += xj * w.y; az += xj * w.z; aw += xj * w.w;
    }

    // ---- bias row j=256 (kept only if 256 < 128+k, i.e. k > 128; Y=1) ----
    if (k > 128 && jo == 0) {
        const float4 w = *reinterpret_cast<const float4*>(Wb + (size_t)256 * H_DIM + h4);
        ax += w.x; ay += w.y; az += w.z; aw += w.w;
    }

    // ---- reduce across the 4 lane-groups (lanes l, l+16, l+32, l+48 share h4) ----
    ax += __shfl_xor(ax, 16); ay += __shfl_xor(ay, 16);
    az += __shfl_xor(az, 16); aw += __shfl_xor(aw, 16);
    ax += __shfl_xor(ax, 32); ay += __shfl_xor(ay, 32);
    az += __shfl_xor(az, 32); aw += __shfl_xor(aw, 32);

    if (lane < 16) {
        float4 r;
        r.x = tanhf(ax); r.y = tanhf(ay); r.z = tanhf(az); r.w = tanhf(aw);
        *reinterpret_cast<float4*>(out + (size_t)b * H_DIM + h4) = r;
    }
}

extern "C" void kernel_launch(void* const* d_in, const int* in_sizes, int n_in,
                              void* d_out, int out_size, void* d_ws, size_t ws_size,
                              hipStream_t stream)
{
    const float* X   = (const float*)d_in[0];
    const float* AUX = (const float*)d_in[1];
    const int*   K   = (const int*)d_in[2];
    float* out = (float*)d_out;

    const int B = in_sizes[2];                 // 16384
    const int blocks = (B + 3) / 4;            // 4 waves (rows) per 256-thread block
    dotmask_kernel<<<blocks, 256, 0, stream>>>(X, AUX, K, out, B);
}